// Round 1
// baseline (210.298 us; speedup 1.0000x reference)
//
#include <hip/hip_runtime.h>
#include <hip/hip_bf16.h>

#define GAT_N 8192
#define GAT_K 256
#define GAT_D 64
#define GAT_ALPHA 0.2f
#define GAT_FILL 1e-15f

typedef float f32x4 __attribute__((ext_vector_type(4)));
typedef short bf16x8 __attribute__((ext_vector_type(8)));

static __device__ __forceinline__ short f2bf(float x) {
  // round-to-nearest-even f32 -> bf16 (no NaN inputs here)
  unsigned u = __float_as_uint(x);
  u += 0x7FFFu + ((u >> 16) & 1u);
  return (short)(u >> 16);
}

// ---------------------------------------------------------------------------
// Kernel 1: Wh = h @ W (f32 in-register), emit:
//   WhT  : bf16 [D][N] transposed copy (B-operand for MFMA in k_attn)
//   s_src: Wh @ a[:D],  s_dst: Wh @ a[D:]
//   tmax : global max of s_dst via monotonic-u32-mapped atomicMax
// grid 128 x 256 threads; each wave computes 16 full rows (lane = column).
// ---------------------------------------------------------------------------
__global__ __launch_bounds__(256) void k_prep(const float* __restrict__ h,
                                              const float* __restrict__ W,
                                              const float* __restrict__ av,
                                              float* __restrict__ s_src,
                                              float* __restrict__ s_dst,
                                              short* __restrict__ WhT,
                                              unsigned* __restrict__ tmax_u) {
  __shared__ float Wl[GAT_K][GAT_D];  // 64 KB
  const int tid = threadIdx.x;
  {
    const f32x4* W4 = (const f32x4*)W;
    f32x4* Wl4 = (f32x4*)&Wl[0][0];
#pragma unroll
    for (int i = 0; i < 16; ++i) Wl4[tid + 256 * i] = W4[tid + 256 * i];
  }
  __syncthreads();
  const int wv = tid >> 6, lane = tid & 63;
  const float a_s = av[lane];
  const float a_d = av[64 + lane];
  const int r0 = blockIdx.x * 64 + wv * 16;
  float wmax = -3.0e38f;
  for (int ii = 0; ii < 16; ++ii) {
    const int row = r0 + ii;
    const f32x4* h4 = (const f32x4*)(h + (size_t)row * GAT_K);
    float acc = 0.f;
#pragma unroll
    for (int k4 = 0; k4 < GAT_K / 4; ++k4) {
      f32x4 hv = h4[k4];
      acc += hv[0] * Wl[4 * k4 + 0][lane];
      acc += hv[1] * Wl[4 * k4 + 1][lane];
      acc += hv[2] * Wl[4 * k4 + 2][lane];
      acc += hv[3] * Wl[4 * k4 + 3][lane];
    }
    WhT[(size_t)lane * GAT_N + row] = f2bf(acc);
    float vs = acc * a_s, vd = acc * a_d;
#pragma unroll
    for (int off = 32; off > 0; off >>= 1) {
      vs += __shfl_xor(vs, off);
      vd += __shfl_xor(vd, off);
    }
    if (lane == 0) { s_src[row] = vs; s_dst[row] = vd; }
    wmax = fmaxf(wmax, vd);  // vd is full row sum in every lane after xor-reduce
  }
  if (lane == 0) {
    unsigned u = __float_as_uint(wmax);
    unsigned m = (u & 0x80000000u) ? ~u : (u | 0x80000000u);
    atomicMax(tmax_u, m);
  }
}

// ---------------------------------------------------------------------------
// Kernel 2: fused masked-softmax + P@Wh, fixed-shift (no online rescale).
// Block = 16 rows, 8 waves split the j-range; P built directly in the MFMA
// 16x16x32 A-fragment layout from coalesced global loads of A. No LDS in the
// main loop; cross-wave partials combined exactly at the end (fixed shift).
// ---------------------------------------------------------------------------
#define BM 16
#define NWAVE 8

__global__ __launch_bounds__(512, 4) void k_attn(
    const float* __restrict__ A,
    const float* __restrict__ s_src,
    const float* __restrict__ s_dst,
    const short* __restrict__ WhT,
    const unsigned* __restrict__ tmax_u,
    float* __restrict__ out) {
  __shared__ float lds_o[NWAVE][BM][GAT_D];  // 32 KB
  __shared__ float lds_l[NWAVE][BM];

  const int tid = threadIdx.x;
  const int wv = tid >> 6, lane = tid & 63;
  const int rsub = lane & 15, kg = lane >> 4;
  const int i0 = blockIdx.x * BM;
  const int row = i0 + rsub;

  const unsigned um = *tmax_u;
  const float tmax = __uint_as_float((um & 0x80000000u) ? (um ^ 0x80000000u) : ~um);
  const float si = s_src[row];
  const float x0 = si + tmax;
  const float mhat = fmaxf(fmaxf(x0, GAT_ALPHA * x0), GAT_FILL);  // >= every logit in row

  f32x4 acc0 = {0.f, 0.f, 0.f, 0.f};
  f32x4 acc1 = {0.f, 0.f, 0.f, 0.f};
  f32x4 acc2 = {0.f, 0.f, 0.f, 0.f};
  f32x4 acc3 = {0.f, 0.f, 0.f, 0.f};
  float lsum = 0.f;

  // per-wave j-slice: j0 = wv*32 + step*256, 32 steps of K=32
  const int jb = wv * 32 + kg * 8;
  const float* pA = A + (size_t)row * GAT_N + jb;
  const float* pt = s_dst + jb;
  const short* pb0 = WhT + (size_t)(0 * 16 + rsub) * GAT_N + jb;
  const short* pb1 = WhT + (size_t)(1 * 16 + rsub) * GAT_N + jb;
  const short* pb2 = WhT + (size_t)(2 * 16 + rsub) * GAT_N + jb;
  const short* pb3 = WhT + (size_t)(3 * 16 + rsub) * GAT_N + jb;

  for (int step = 0; step < GAT_N / (32 * NWAVE); ++step) {
    const int off = step * 256;
    f32x4 av0 = *(const f32x4*)(pA + off);
    f32x4 av1 = *(const f32x4*)(pA + off + 4);
    f32x4 tv0 = *(const f32x4*)(pt + off);
    f32x4 tv1 = *(const f32x4*)(pt + off + 4);
    bf16x8 b0 = *(const bf16x8*)(pb0 + off);
    bf16x8 b1 = *(const bf16x8*)(pb1 + off);
    bf16x8 b2 = *(const bf16x8*)(pb2 + off);
    bf16x8 b3 = *(const bf16x8*)(pb3 + off);

    bf16x8 af;
#pragma unroll
    for (int e = 0; e < 4; ++e) {
      float x = si + tv0[e];
      float v = fmaxf(x, GAT_ALPHA * x);
      v = (av0[e] > 0.f) ? v : GAT_FILL;
      float pe = __expf(v - mhat);
      lsum += pe;
      af[e] = f2bf(pe);
    }
#pragma unroll
    for (int e = 0; e < 4; ++e) {
      float x = si + tv1[e];
      float v = fmaxf(x, GAT_ALPHA * x);
      v = (av1[e] > 0.f) ? v : GAT_FILL;
      float pe = __expf(v - mhat);
      lsum += pe;
      af[4 + e] = f2bf(pe);
    }

    acc0 = __builtin_amdgcn_mfma_f32_16x16x32_bf16(af, b0, acc0, 0, 0, 0);
    acc1 = __builtin_amdgcn_mfma_f32_16x16x32_bf16(af, b1, acc1, 0, 0, 0);
    acc2 = __builtin_amdgcn_mfma_f32_16x16x32_bf16(af, b2, acc2, 0, 0, 0);
    acc3 = __builtin_amdgcn_mfma_f32_16x16x32_bf16(af, b3, acc3, 0, 0, 0);
  }

  // reduce lsum across the 4 k-groups (lanes with same rsub)
  lsum += __shfl_xor(lsum, 16);
  lsum += __shfl_xor(lsum, 32);

  // spill per-wave partials (C/D layout: col = lane&15, row = kg*4 + reg)
#pragma unroll
  for (int r = 0; r < 4; ++r) lds_o[wv][kg * 4 + r][0 * 16 + rsub] = acc0[r];
#pragma unroll
  for (int r = 0; r < 4; ++r) lds_o[wv][kg * 4 + r][1 * 16 + rsub] = acc1[r];
#pragma unroll
  for (int r = 0; r < 4; ++r) lds_o[wv][kg * 4 + r][2 * 16 + rsub] = acc2[r];
#pragma unroll
  for (int r = 0; r < 4; ++r) lds_o[wv][kg * 4 + r][3 * 16 + rsub] = acc3[r];
  if (lane < 16) lds_l[wv][lane] = lsum;
  __syncthreads();

  // exact cross-wave combine (fixed shift) + ELU + store
  for (int idx = tid; idx < BM * GAT_D; idx += 512) {
    const int r = idx >> 6, c = idx & 63;
    float o = 0.f, ll = 0.f;
#pragma unroll
    for (int w = 0; w < NWAVE; ++w) {
      o += lds_o[w][r][c];
      ll += lds_l[w][r];
    }
    float val = o / ll;
    out[(size_t)(i0 + r) * GAT_D + c] = (val > 0.f) ? val : (__expf(val) - 1.f);
  }
}

// ---------------------------------------------------------------------------
extern "C" void kernel_launch(void* const* d_in, const int* in_sizes, int n_in,
                              void* d_out, int out_size, void* d_ws, size_t ws_size,
                              hipStream_t stream) {
  const float* h = (const float*)d_in[0];
  const float* A = (const float*)d_in[1];
  const float* W = (const float*)d_in[2];
  const float* a = (const float*)d_in[3];
  float* out = (float*)d_out;

  // ws layout: [0,4) tmax_u | [256,+32K) s_src | [33024,+32K) s_dst | [65792,+1M) WhT
  const size_t need = 65792 + (size_t)GAT_D * GAT_N * 2;
  if (ws_size < need) return;
  unsigned* tmax_u = (unsigned*)d_ws;
  float* s_src = (float*)((char*)d_ws + 256);
  float* s_dst = (float*)((char*)d_ws + 33024);
  short* WhT = (short*)((char*)d_ws + 65792);

  (void)hipMemsetAsync(d_ws, 0, 4, stream);  // tmax = mapped(-inf)
  k_prep<<<dim3(GAT_N / 64), dim3(256), 0, stream>>>(h, W, a, s_src, s_dst, WhT, tmax_u);
  k_attn<<<dim3(GAT_N / BM), dim3(512), 0, stream>>>(A, s_src, s_dst, WhT, tmax_u, out);
}

// Round 2
// 164.252 us; speedup vs baseline: 1.2803x; 1.2803x over previous
//
#include <hip/hip_runtime.h>
#include <hip/hip_bf16.h>

#define GAT_N 8192
#define GAT_K 256
#define GAT_D 64
#define GAT_ALPHA 0.2f
#define GAT_FILL 1e-15f

typedef float f32x4 __attribute__((ext_vector_type(4)));
typedef short bf16x8 __attribute__((ext_vector_type(8)));

static __device__ __forceinline__ short f2bf(float x) {
  // round-to-nearest-even f32 -> bf16 (no NaN inputs here)
  unsigned u = __float_as_uint(x);
  u += 0x7FFFu + ((u >> 16) & 1u);
  return (short)(u >> 16);
}

// ---------------------------------------------------------------------------
// Kernel 1: Wh = h @ W (f32 in-register), emit:
//   WhT  : bf16 [D][N] transposed copy (B-operand for MFMA in k_attn)
//   s_src: Wh @ a[:D],  s_dst: Wh @ a[D:]
//   bmax : per-block max of s_dst (k_attn reduces these; no atomics/memset)
// grid 256 x 256 threads; each wave computes 8 full rows (lane = column).
// ---------------------------------------------------------------------------
__global__ __launch_bounds__(256) void k_prep(const float* __restrict__ h,
                                              const float* __restrict__ W,
                                              const float* __restrict__ av,
                                              float* __restrict__ s_src,
                                              float* __restrict__ s_dst,
                                              short* __restrict__ WhT,
                                              float* __restrict__ bmax) {
  __shared__ float Wl[GAT_K][GAT_D];  // 64 KB
  __shared__ float wmLds[4];
  const int tid = threadIdx.x;
  {
    const f32x4* W4 = (const f32x4*)W;
    f32x4* Wl4 = (f32x4*)&Wl[0][0];
#pragma unroll
    for (int i = 0; i < 16; ++i) Wl4[tid + 256 * i] = W4[tid + 256 * i];
  }
  __syncthreads();
  const int wv = tid >> 6, lane = tid & 63;
  const float a_s = av[lane];
  const float a_d = av[64 + lane];
  const int r0 = blockIdx.x * 32 + wv * 8;
  float wmax = -3.0e38f;
  for (int ii = 0; ii < 8; ++ii) {
    const int row = r0 + ii;
    const f32x4* h4 = (const f32x4*)(h + (size_t)row * GAT_K);
    float acc = 0.f;
#pragma unroll
    for (int k4 = 0; k4 < GAT_K / 4; ++k4) {
      f32x4 hv = h4[k4];
      acc += hv[0] * Wl[4 * k4 + 0][lane];
      acc += hv[1] * Wl[4 * k4 + 1][lane];
      acc += hv[2] * Wl[4 * k4 + 2][lane];
      acc += hv[3] * Wl[4 * k4 + 3][lane];
    }
    WhT[(size_t)lane * GAT_N + row] = f2bf(acc);
    float vs = acc * a_s, vd = acc * a_d;
#pragma unroll
    for (int off = 32; off > 0; off >>= 1) {
      vs += __shfl_xor(vs, off);
      vd += __shfl_xor(vd, off);
    }
    if (lane == 0) { s_src[row] = vs; s_dst[row] = vd; }
    wmax = fmaxf(wmax, vd);  // vd is full row sum in every lane after xor-reduce
  }
  if (lane == 0) wmLds[wv] = wmax;
  __syncthreads();
  if (tid == 0) {
    bmax[blockIdx.x] = fmaxf(fmaxf(wmLds[0], wmLds[1]), fmaxf(wmLds[2], wmLds[3]));
  }
}

// ---------------------------------------------------------------------------
// Kernel 2: fused masked-softmax + P@Wh, fixed-shift (no online rescale).
// Block = 16 rows, 8 waves split the j-range; P built directly in the MFMA
// 16x16x32 A-fragment layout from coalesced global loads of A. No LDS in the
// main loop; cross-wave partials combined exactly at the end (fixed shift).
// ---------------------------------------------------------------------------
#define BM 16
#define NWAVE 8

__global__ __launch_bounds__(512, 4) void k_attn(
    const float* __restrict__ A,
    const float* __restrict__ s_src,
    const float* __restrict__ s_dst,
    const short* __restrict__ WhT,
    const float* __restrict__ bmax,
    float* __restrict__ out) {
  __shared__ float lds_o[NWAVE][BM][GAT_D];  // 32 KB
  __shared__ float lds_l[NWAVE][BM];

  const int tid = threadIdx.x;
  const int wv = tid >> 6, lane = tid & 63;
  const int rsub = lane & 15, kg = lane >> 4;
  const int i0 = blockIdx.x * BM;
  const int row = i0 + rsub;

  // global max of s_dst from 256 per-block maxima (written by k_prep)
  float bm = fmaxf(fmaxf(bmax[lane], bmax[lane + 64]),
                   fmaxf(bmax[lane + 128], bmax[lane + 192]));
#pragma unroll
  for (int off = 32; off > 0; off >>= 1) bm = fmaxf(bm, __shfl_xor(bm, off));
  const float tmax = bm;

  const float si = s_src[row];
  const float x0 = si + tmax;
  const float mhat = fmaxf(fmaxf(x0, GAT_ALPHA * x0), GAT_FILL);  // >= every logit in row

  f32x4 acc0 = {0.f, 0.f, 0.f, 0.f};
  f32x4 acc1 = {0.f, 0.f, 0.f, 0.f};
  f32x4 acc2 = {0.f, 0.f, 0.f, 0.f};
  f32x4 acc3 = {0.f, 0.f, 0.f, 0.f};
  float lsum = 0.f;

  // per-wave j-slice: j0 = wv*32 + step*256, 32 steps of K=32
  const int jb = wv * 32 + kg * 8;
  const float* pA = A + (size_t)row * GAT_N + jb;
  const float* pt = s_dst + jb;
  const short* pb0 = WhT + (size_t)(0 * 16 + rsub) * GAT_N + jb;
  const short* pb1 = WhT + (size_t)(1 * 16 + rsub) * GAT_N + jb;
  const short* pb2 = WhT + (size_t)(2 * 16 + rsub) * GAT_N + jb;
  const short* pb3 = WhT + (size_t)(3 * 16 + rsub) * GAT_N + jb;

  for (int step = 0; step < GAT_N / (32 * NWAVE); ++step) {
    const int off = step * 256;
    f32x4 av0 = *(const f32x4*)(pA + off);
    f32x4 av1 = *(const f32x4*)(pA + off + 4);
    f32x4 tv0 = *(const f32x4*)(pt + off);
    f32x4 tv1 = *(const f32x4*)(pt + off + 4);
    bf16x8 b0 = *(const bf16x8*)(pb0 + off);
    bf16x8 b1 = *(const bf16x8*)(pb1 + off);
    bf16x8 b2 = *(const bf16x8*)(pb2 + off);
    bf16x8 b3 = *(const bf16x8*)(pb3 + off);

    bf16x8 af;
#pragma unroll
    for (int e = 0; e < 4; ++e) {
      float x = si + tv0[e];
      float v = fmaxf(x, GAT_ALPHA * x);
      v = (av0[e] > 0.f) ? v : GAT_FILL;
      float pe = __expf(v - mhat);
      lsum += pe;
      af[e] = f2bf(pe);
    }
#pragma unroll
    for (int e = 0; e < 4; ++e) {
      float x = si + tv1[e];
      float v = fmaxf(x, GAT_ALPHA * x);
      v = (av1[e] > 0.f) ? v : GAT_FILL;
      float pe = __expf(v - mhat);
      lsum += pe;
      af[4 + e] = f2bf(pe);
    }

    acc0 = __builtin_amdgcn_mfma_f32_16x16x32_bf16(af, b0, acc0, 0, 0, 0);
    acc1 = __builtin_amdgcn_mfma_f32_16x16x32_bf16(af, b1, acc1, 0, 0, 0);
    acc2 = __builtin_amdgcn_mfma_f32_16x16x32_bf16(af, b2, acc2, 0, 0, 0);
    acc3 = __builtin_amdgcn_mfma_f32_16x16x32_bf16(af, b3, acc3, 0, 0, 0);
  }

  // reduce lsum across the 4 k-groups (lanes with same rsub)
  lsum += __shfl_xor(lsum, 16);
  lsum += __shfl_xor(lsum, 32);

  // spill per-wave partials (C/D layout: col = lane&15, row = kg*4 + reg)
#pragma unroll
  for (int r = 0; r < 4; ++r) lds_o[wv][kg * 4 + r][0 * 16 + rsub] = acc0[r];
#pragma unroll
  for (int r = 0; r < 4; ++r) lds_o[wv][kg * 4 + r][1 * 16 + rsub] = acc1[r];
#pragma unroll
  for (int r = 0; r < 4; ++r) lds_o[wv][kg * 4 + r][2 * 16 + rsub] = acc2[r];
#pragma unroll
  for (int r = 0; r < 4; ++r) lds_o[wv][kg * 4 + r][3 * 16 + rsub] = acc3[r];
  if (lane < 16) lds_l[wv][lane] = lsum;
  __syncthreads();

  // exact cross-wave combine (fixed shift) + ELU + store
  for (int idx = tid; idx < BM * GAT_D; idx += 512) {
    const int r = idx >> 6, c = idx & 63;
    float o = 0.f, ll = 0.f;
#pragma unroll
    for (int w = 0; w < NWAVE; ++w) {
      o += lds_o[w][r][c];
      ll += lds_l[w][r];
    }
    float val = o / ll;
    out[(size_t)(i0 + r) * GAT_D + c] = (val > 0.f) ? val : (__expf(val) - 1.f);
  }
}

// ---------------------------------------------------------------------------
extern "C" void kernel_launch(void* const* d_in, const int* in_sizes, int n_in,
                              void* d_out, int out_size, void* d_ws, size_t ws_size,
                              hipStream_t stream) {
  const float* h = (const float*)d_in[0];
  const float* A = (const float*)d_in[1];
  const float* W = (const float*)d_in[2];
  const float* a = (const float*)d_in[3];
  float* out = (float*)d_out;

  // ws layout: [0,1K) bmax | [4K,+32K) s_src | [36864,+32K) s_dst | [69632,+1M) WhT
  const size_t need = 69632 + (size_t)GAT_D * GAT_N * 2;
  if (ws_size < need) return;
  float* bmax = (float*)d_ws;
  float* s_src = (float*)((char*)d_ws + 4096);
  float* s_dst = (float*)((char*)d_ws + 36864);
  short* WhT = (short*)((char*)d_ws + 69632);

  k_prep<<<dim3(256), dim3(256), 0, stream>>>(h, W, a, s_src, s_dst, WhT, bmax);
  k_attn<<<dim3(GAT_N / BM), dim3(512), 0, stream>>>(A, s_src, s_dst, WhT, bmax, out);
}

// Round 3
// 150.208 us; speedup vs baseline: 1.4000x; 1.0935x over previous
//
#include <hip/hip_runtime.h>
#include <hip/hip_bf16.h>

#define GAT_N 8192
#define GAT_K 256
#define GAT_D 64
#define GAT_ALPHA 0.2f
#define GAT_FILL 1e-15f

typedef float f32x4 __attribute__((ext_vector_type(4)));
typedef short bf16x8 __attribute__((ext_vector_type(8)));

static __device__ __forceinline__ unsigned f2bf_u(float x) {
  // round-to-nearest-even f32 -> bf16 (in low 16 bits)
  unsigned u = __float_as_uint(x);
  u += 0x7FFFu + ((u >> 16) & 1u);
  return u >> 16;
}

static __device__ __forceinline__ float rfl(float x) {
  return __uint_as_float(__builtin_amdgcn_readfirstlane(__float_as_uint(x)));
}

// ---------------------------------------------------------------------------
// Kernel 1: Wh = h @ W (f32 in-register), emit:
//   WhT  : bf16 [D][N] transposed copy (B-operand for MFMA in k_attn)
//   s_src: Wh @ a[:D],  s_dst: Wh @ a[D:]
//   bmax : per-block max of s_dst (k_attn reduces these; no atomics/memset)
// ---------------------------------------------------------------------------
__global__ __launch_bounds__(256) void k_prep(const float* __restrict__ h,
                                              const float* __restrict__ W,
                                              const float* __restrict__ av,
                                              float* __restrict__ s_src,
                                              float* __restrict__ s_dst,
                                              short* __restrict__ WhT,
                                              float* __restrict__ bmax) {
  __shared__ float Wl[GAT_K][GAT_D];  // 64 KB
  __shared__ float wmLds[4];
  const int tid = threadIdx.x;
  {
    const f32x4* W4 = (const f32x4*)W;
    f32x4* Wl4 = (f32x4*)&Wl[0][0];
#pragma unroll
    for (int i = 0; i < 16; ++i) Wl4[tid + 256 * i] = W4[tid + 256 * i];
  }
  __syncthreads();
  const int wv = tid >> 6, lane = tid & 63;
  const float a_s = av[lane];
  const float a_d = av[64 + lane];
  const int r0 = blockIdx.x * 32 + wv * 8;
  float wmax = -3.0e38f;
  for (int ii = 0; ii < 8; ++ii) {
    const int row = r0 + ii;
    const f32x4* h4 = (const f32x4*)(h + (size_t)row * GAT_K);
    float acc = 0.f;
#pragma unroll
    for (int k4 = 0; k4 < GAT_K / 4; ++k4) {
      f32x4 hv = h4[k4];
      acc += hv[0] * Wl[4 * k4 + 0][lane];
      acc += hv[1] * Wl[4 * k4 + 1][lane];
      acc += hv[2] * Wl[4 * k4 + 2][lane];
      acc += hv[3] * Wl[4 * k4 + 3][lane];
    }
    WhT[(size_t)lane * GAT_N + row] = (short)f2bf_u(acc);
    float vs = acc * a_s, vd = acc * a_d;
#pragma unroll
    for (int off = 32; off > 0; off >>= 1) {
      vs += __shfl_xor(vs, off);
      vd += __shfl_xor(vd, off);
    }
    if (lane == 0) { s_src[row] = vs; s_dst[row] = vd; }
    wmax = fmaxf(wmax, vd);
  }
  if (lane == 0) wmLds[wv] = wmax;
  __syncthreads();
  if (tid == 0) {
    bmax[blockIdx.x] = fmaxf(fmaxf(wmLds[0], wmLds[1]), fmaxf(wmLds[2], wmLds[3]));
  }
}

// ---------------------------------------------------------------------------
// Kernel 2: fused masked-softmax + P@Wh, fixed-shift softmax.
// Block = 16 rows, 8 waves split the j-range (1024 cols each, 4 steps x 256).
// Per step each wave:
//   1) loads A row-by-row, 1 KB contiguous per wave-instruction (coalesced),
//   2) computes P = exp(lrelu-masked - mhat) in f32, packs bf16,
//   3) stages P into a wave-private XOR-swizzled LDS tile [16][256],
//   4) ds_read_b128 A-fragments + global (L2) B-fragments -> 5 MFMAs/kq
//      (4 output quadrants + 1 all-ones B for the row-sum lsum).
// No block barrier in the main loop. Exact cross-wave combine at the end.
// ---------------------------------------------------------------------------
#define BM 16
#define NWAVE 8

__global__ __launch_bounds__(512, 4) void k_attn(
    const float* __restrict__ A,
    const float* __restrict__ s_src,
    const float* __restrict__ s_dst,
    const short* __restrict__ WhT,
    const float* __restrict__ bmax,
    float* __restrict__ out) {
  __shared__ char smem[65536];  // P tiles: 8 waves x [16][256] bf16 (8 KB each)

  const int tid = threadIdx.x;
  const int wv = tid >> 6, lane = tid & 63;
  const int rsub = lane & 15, kg = lane >> 4;
  const int i0 = blockIdx.x * BM;
  const int wvbase = wv * 8192;

  // global max of s_dst from 256 per-block maxima
  float bm = fmaxf(fmaxf(bmax[lane], bmax[lane + 64]),
                   fmaxf(bmax[lane + 128], bmax[lane + 192]));
#pragma unroll
  for (int off = 32; off > 0; off >>= 1) bm = fmaxf(bm, __shfl_xor(bm, off));
  const float tmax = bm;

  // per-row uniform scalars (forced to SGPR)
  float si_[BM], mh_[BM];
#pragma unroll
  for (int r = 0; r < BM; ++r) {
    float s = s_src[i0 + r];
    float x0 = s + tmax;
    float m = fmaxf(fmaxf(x0, GAT_ALPHA * x0), GAT_FILL);
    si_[r] = rfl(s);
    mh_[r] = rfl(m);
  }

  bf16x8 ones;
#pragma unroll
  for (int e = 0; e < 8; ++e) ones[e] = (short)0x3F80;  // bf16 1.0

  f32x4 acc0 = {0.f, 0.f, 0.f, 0.f};
  f32x4 acc1 = {0.f, 0.f, 0.f, 0.f};
  f32x4 acc2 = {0.f, 0.f, 0.f, 0.f};
  f32x4 acc3 = {0.f, 0.f, 0.f, 0.f};
  f32x4 accl = {0.f, 0.f, 0.f, 0.f};

  const short* pb0 = WhT + (size_t)(0 * 16 + rsub) * GAT_N;
  const short* pb1 = WhT + (size_t)(1 * 16 + rsub) * GAT_N;
  const short* pb2 = WhT + (size_t)(2 * 16 + rsub) * GAT_N;
  const short* pb3 = WhT + (size_t)(3 * 16 + rsub) * GAT_N;

  for (int step = 0; step < GAT_N / (256 * NWAVE); ++step) {
    const int jc = step * 2048 + wv * 256;
    const float* At = A + (size_t)i0 * GAT_N + jc + lane * 4;
    const f32x4 tj = *(const f32x4*)(s_dst + jc + lane * 4);

    // ---- stage P: two batches of 8 rows, coalesced 1 KB loads ----
#pragma unroll
    for (int half = 0; half < 2; ++half) {
      f32x4 aA[8];
#pragma unroll
      for (int r = 0; r < 8; ++r)
        aA[r] = *(const f32x4*)(At + (size_t)(half * 8 + r) * GAT_N);
#pragma unroll
      for (int r = 0; r < 8; ++r) {
        const int row = half * 8 + r;
        const float si = si_[row], mh = mh_[row];
        unsigned pk[4];
#pragma unroll
        for (int e = 0; e < 4; ++e) {
          float x = si + tj[e];
          float v = fmaxf(x, GAT_ALPHA * x);
          v = (aA[r][e] > 0.f) ? v : GAT_FILL;
          pk[e] = f2bf_u(__expf(v - mh));
        }
        uint2 w;
        w.x = pk[0] | (pk[1] << 16);
        w.y = pk[2] | (pk[3] << 16);
        const int addr = wvbase + (row << 9) + (((lane << 3)) ^ ((row & 7) << 4));
        *(uint2*)(&smem[addr]) = w;
      }
    }

    // ---- MFMA over 8 k-quads of 32 ----
#pragma unroll
    for (int kq = 0; kq < 8; ++kq) {
      const int raddr = wvbase + (rsub << 9) + (((kq << 6) | (kg << 4)) ^ ((rsub & 7) << 4));
      bf16x8 af = *(const bf16x8*)(&smem[raddr]);
      const int bcol = jc + kq * 32 + kg * 8;
      bf16x8 b0 = *(const bf16x8*)(pb0 + bcol);
      bf16x8 b1 = *(const bf16x8*)(pb1 + bcol);
      bf16x8 b2 = *(const bf16x8*)(pb2 + bcol);
      bf16x8 b3 = *(const bf16x8*)(pb3 + bcol);
      acc0 = __builtin_amdgcn_mfma_f32_16x16x32_bf16(af, b0, acc0, 0, 0, 0);
      acc1 = __builtin_amdgcn_mfma_f32_16x16x32_bf16(af, b1, acc1, 0, 0, 0);
      acc2 = __builtin_amdgcn_mfma_f32_16x16x32_bf16(af, b2, acc2, 0, 0, 0);
      acc3 = __builtin_amdgcn_mfma_f32_16x16x32_bf16(af, b3, acc3, 0, 0, 0);
      accl = __builtin_amdgcn_mfma_f32_16x16x32_bf16(af, ones, accl, 0, 0, 0);
    }
  }

  __syncthreads();  // all waves done with P tiles; reuse smem for epilogue

  float* lds_o = (float*)smem;             // [NWAVE][BM][GAT_D] = 32 KB
  float* lds_l = (float*)(smem + 32768);   // [NWAVE][BM]
  // C/D layout: col = lane&15, row = kg*4 + reg
#pragma unroll
  for (int r = 0; r < 4; ++r) {
    const int orow = kg * 4 + r;
    lds_o[wv * 1024 + orow * 64 + 0 * 16 + rsub] = acc0[r];
    lds_o[wv * 1024 + orow * 64 + 1 * 16 + rsub] = acc1[r];
    lds_o[wv * 1024 + orow * 64 + 2 * 16 + rsub] = acc2[r];
    lds_o[wv * 1024 + orow * 64 + 3 * 16 + rsub] = acc3[r];
    if (rsub == 0) lds_l[wv * 16 + orow] = accl[r];  // rowsum replicated over cols
  }
  __syncthreads();

  for (int idx = tid; idx < BM * GAT_D; idx += 512) {
    const int r = idx >> 6, c = idx & 63;
    float o = 0.f, ll = 0.f;
#pragma unroll
    for (int w = 0; w < NWAVE; ++w) {
      o += lds_o[w * 1024 + r * 64 + c];
      ll += lds_l[w * 16 + r];
    }
    float val = o / ll;
    out[(size_t)(i0 + r) * GAT_D + c] = (val > 0.f) ? val : (__expf(val) - 1.f);
  }
}

// ---------------------------------------------------------------------------
extern "C" void kernel_launch(void* const* d_in, const int* in_sizes, int n_in,
                              void* d_out, int out_size, void* d_ws, size_t ws_size,
                              hipStream_t stream) {
  const float* h = (const float*)d_in[0];
  const float* A = (const float*)d_in[1];
  const float* W = (const float*)d_in[2];
  const float* a = (const float*)d_in[3];
  float* out = (float*)d_out;

  // ws layout: [0,1K) bmax | [4K,+32K) s_src | [36864,+32K) s_dst | [69632,+1M) WhT
  const size_t need = 69632 + (size_t)GAT_D * GAT_N * 2;
  if (ws_size < need) return;
  float* bmax = (float*)d_ws;
  float* s_src = (float*)((char*)d_ws + 4096);
  float* s_dst = (float*)((char*)d_ws + 36864);
  short* WhT = (short*)((char*)d_ws + 69632);

  k_prep<<<dim3(256), dim3(256), 0, stream>>>(h, W, a, s_src, s_dst, WhT, bmax);
  k_attn<<<dim3(GAT_N / BM), dim3(512), 0, stream>>>(A, s_src, s_dst, WhT, bmax, out);
}

// Round 4
// 133.637 us; speedup vs baseline: 1.5737x; 1.1240x over previous
//
#include <hip/hip_runtime.h>
#include <hip/hip_bf16.h>

#define GAT_N 8192
#define GAT_K 256
#define GAT_D 64
#define GAT_ALPHA 0.2f
#define GAT_FILL 1e-15f

typedef float f32x4 __attribute__((ext_vector_type(4)));
typedef short bf16x8 __attribute__((ext_vector_type(8)));

static __device__ __forceinline__ unsigned f2bf_u(float x) {
  unsigned u = __float_as_uint(x);
  u += 0x7FFFu + ((u >> 16) & 1u);
  return u >> 16;
}

static __device__ __forceinline__ float rfl(float x) {
  return __uint_as_float(__builtin_amdgcn_readfirstlane(__float_as_uint(x)));
}

static __device__ __forceinline__ f32x4 ntload(const float* p) {
  return __builtin_nontemporal_load((const f32x4*)p);
}

// ---------------------------------------------------------------------------
// Kernel 1: register-tiled Wh = h @ W (no LDS for W):
//   per wave: 8 rows; K chunked by 32, W-chunk held in 32 VGPRs (coalesced
//   L2-hit loads), h elements are wave-uniform loads. Dual accumulators
//   break the FMA latency chain. WhT written 16B/lane via a tiny LDS
//   transpose (was 2B scatter).
// ---------------------------------------------------------------------------
__global__ __launch_bounds__(256) void k_prep(const float* __restrict__ h,
                                              const float* __restrict__ W,
                                              const float* __restrict__ av,
                                              float* __restrict__ s_src,
                                              float* __restrict__ s_dst,
                                              short* __restrict__ WhT,
                                              float* __restrict__ bmax) {
  __shared__ short T[4][64][8];  // 4 KB transpose staging
  __shared__ float wmLds[4];
  const int tid = threadIdx.x;
  const int wv = tid >> 6, lane = tid & 63;
  const int r0 = blockIdx.x * 32 + wv * 8;

  float acc[8], acc2[8];
#pragma unroll
  for (int r = 0; r < 8; ++r) { acc[r] = 0.f; acc2[r] = 0.f; }

  for (int kc = 0; kc < GAT_K; kc += 32) {
    float Wreg[32];
#pragma unroll
    for (int e = 0; e < 32; ++e) Wreg[e] = W[(size_t)(kc + e) * GAT_D + lane];
#pragma unroll
    for (int r = 0; r < 8; ++r) {
      const f32x4* h4 = (const f32x4*)(h + (size_t)(r0 + r) * GAT_K + kc);
#pragma unroll
      for (int q = 0; q < 8; ++q) {
        f32x4 hv = h4[q];
        acc[r] += hv[0] * Wreg[4 * q + 0];
        acc2[r] += hv[1] * Wreg[4 * q + 1];
        acc[r] += hv[2] * Wreg[4 * q + 2];
        acc2[r] += hv[3] * Wreg[4 * q + 3];
      }
    }
  }

  const float a_s = av[lane];
  const float a_d = av[64 + lane];
  float wmax = -3.0e38f;
#pragma unroll
  for (int r = 0; r < 8; ++r) {
    const float accf = acc[r] + acc2[r];
    T[wv][lane][r] = (short)f2bf_u(accf);
    float vs = accf * a_s, vd = accf * a_d;
#pragma unroll
    for (int off = 32; off > 0; off >>= 1) {
      vs += __shfl_xor(vs, off);
      vd += __shfl_xor(vd, off);
    }
    if (lane == 0) { s_src[r0 + r] = vs; s_dst[r0 + r] = vd; }
    wmax = fmaxf(wmax, vd);
  }
  // 16B-per-lane WhT write: row d = lane, cols r0..r0+8
  bf16x8 vt = *(const bf16x8*)&T[wv][lane][0];
  *(bf16x8*)(WhT + (size_t)lane * GAT_N + r0) = vt;

  if (lane == 0) wmLds[wv] = wmax;
  __syncthreads();
  if (tid == 0) {
    bmax[blockIdx.x] = fmaxf(fmaxf(wmLds[0], wmLds[1]), fmaxf(wmLds[2], wmLds[3]));
  }
}

// ---------------------------------------------------------------------------
// Kernel 2: fused masked-softmax + P@Wh, fixed-shift softmax.
// Block = 16 rows x 2048-col chunks. Stage phase: the WHOLE block reads one
// A row-segment at a time (8 KB fully contiguous, nontemporal), computes P,
// stores to a shared XOR-swizzled [16][2048] bf16 tile. MFMA phase: each of
// the 8 waves consumes its disjoint 256-col slice (8 kq x 5 MFMAs, +ones
// B-fragment accumulating the row-sum). Exact cross-wave combine at the end
// (fixed shift => partials add exactly).
// ---------------------------------------------------------------------------
#define BM 16
#define JB 2048
#define NWAVE 8

__global__ __launch_bounds__(512, 4) void k_attn(
    const float* __restrict__ A,
    const float* __restrict__ s_src,
    const float* __restrict__ s_dst,
    const short* __restrict__ WhT,
    const float* __restrict__ bmax,
    float* __restrict__ out) {
  __shared__ char smem[65536];  // P tile [16][2048] bf16 (swizzled); epilogue reuse

  const int tid = threadIdx.x;
  const int wv = tid >> 6, lane = tid & 63;
  const int rsub = lane & 15, kg = lane >> 4;
  const int i0 = blockIdx.x * BM;

  // global max of s_dst from 256 per-block maxima
  float bm = fmaxf(fmaxf(bmax[lane], bmax[lane + 64]),
                   fmaxf(bmax[lane + 128], bmax[lane + 192]));
#pragma unroll
  for (int off = 32; off > 0; off >>= 1) bm = fmaxf(bm, __shfl_xor(bm, off));
  const float tmax = bm;

  float si_[BM], mh_[BM];
#pragma unroll
  for (int r = 0; r < BM; ++r) {
    float s = s_src[i0 + r];
    float x0 = s + tmax;
    float m = fmaxf(fmaxf(x0, GAT_ALPHA * x0), GAT_FILL);
    si_[r] = rfl(s);
    mh_[r] = rfl(m);
  }

  bf16x8 ones;
#pragma unroll
  for (int e = 0; e < 8; ++e) ones[e] = (short)0x3F80;

  f32x4 acc0 = {0.f, 0.f, 0.f, 0.f};
  f32x4 acc1 = {0.f, 0.f, 0.f, 0.f};
  f32x4 acc2 = {0.f, 0.f, 0.f, 0.f};
  f32x4 acc3 = {0.f, 0.f, 0.f, 0.f};
  f32x4 accl = {0.f, 0.f, 0.f, 0.f};

  const short* pb0 = WhT + (size_t)(0 * 16 + rsub) * GAT_N;
  const short* pb1 = WhT + (size_t)(1 * 16 + rsub) * GAT_N;
  const short* pb2 = WhT + (size_t)(2 * 16 + rsub) * GAT_N;
  const short* pb3 = WhT + (size_t)(3 * 16 + rsub) * GAT_N;

  for (int chunk = 0; chunk < GAT_N / JB; ++chunk) {
    const int jc = chunk * JB;
    const f32x4 tj = *(const f32x4*)(s_dst + jc + tid * 4);  // reused for 16 rows
    const float* Abase = A + (size_t)i0 * GAT_N + jc + tid * 4;

    // ---- stage phase: one 8KB contiguous row-segment at a time ----
    f32x4 a_cur = ntload(Abase);
#pragma unroll
    for (int r = 0; r < BM; ++r) {
      f32x4 a_nxt;
      if (r < BM - 1) a_nxt = ntload(Abase + (size_t)(r + 1) * GAT_N);
      const float si = si_[r], mh = mh_[r];
      unsigned pk[4];
#pragma unroll
      for (int e = 0; e < 4; ++e) {
        float x = si + tj[e];
        float v = fmaxf(x, GAT_ALPHA * x);
        v = (a_cur[e] > 0.f) ? v : GAT_FILL;
        pk[e] = f2bf_u(__expf(v - mh));
      }
      uint2 w;
      w.x = pk[0] | (pk[1] << 16);
      w.y = pk[2] | (pk[3] << 16);
      *(uint2*)(&smem[(r << 12) + ((tid << 3) ^ ((r & 7) << 4))]) = w;
      a_cur = a_nxt;
    }
    __syncthreads();

    // ---- MFMA phase: wave wv consumes cols [jc + wv*256, +256) ----
#pragma unroll
    for (int kq = 0; kq < 8; ++kq) {
      const int cb = (wv << 9) + (kq << 6) + (kg << 4);  // byte col in row
      bf16x8 af = *(const bf16x8*)(&smem[(rsub << 12) + (cb ^ ((rsub & 7) << 4))]);
      const int bcol = jc + (wv << 8) + (kq << 5) + (kg << 3);
      bf16x8 b0 = *(const bf16x8*)(pb0 + bcol);
      bf16x8 b1 = *(const bf16x8*)(pb1 + bcol);
      bf16x8 b2 = *(const bf16x8*)(pb2 + bcol);
      bf16x8 b3 = *(const bf16x8*)(pb3 + bcol);
      acc0 = __builtin_amdgcn_mfma_f32_16x16x32_bf16(af, b0, acc0, 0, 0, 0);
      acc1 = __builtin_amdgcn_mfma_f32_16x16x32_bf16(af, b1, acc1, 0, 0, 0);
      acc2 = __builtin_amdgcn_mfma_f32_16x16x32_bf16(af, b2, acc2, 0, 0, 0);
      acc3 = __builtin_amdgcn_mfma_f32_16x16x32_bf16(af, b3, acc3, 0, 0, 0);
      accl = __builtin_amdgcn_mfma_f32_16x16x32_bf16(af, ones, accl, 0, 0, 0);
    }
    __syncthreads();  // protect tile before next stage overwrites
  }

  // ---- epilogue: exact cross-wave combine + ELU (smem reused) ----
  float* lds_o = (float*)smem;            // [8][16][64] f32 = 32 KB
  float* lds_l = (float*)(smem + 32768);  // [8][16]
#pragma unroll
  for (int r = 0; r < 4; ++r) {
    const int orow = kg * 4 + r;  // C/D layout: col = lane&15, row = kg*4+reg
    lds_o[wv * 1024 + orow * 64 + 0 * 16 + rsub] = acc0[r];
    lds_o[wv * 1024 + orow * 64 + 1 * 16 + rsub] = acc1[r];
    lds_o[wv * 1024 + orow * 64 + 2 * 16 + rsub] = acc2[r];
    lds_o[wv * 1024 + orow * 64 + 3 * 16 + rsub] = acc3[r];
    if (rsub == 0) lds_l[wv * 16 + orow] = accl[r];
  }
  __syncthreads();

  for (int idx = tid; idx < BM * GAT_D; idx += 512) {
    const int r = idx >> 6, c = idx & 63;
    float o = 0.f, ll = 0.f;
#pragma unroll
    for (int w = 0; w < NWAVE; ++w) {
      o += lds_o[w * 1024 + r * 64 + c];
      ll += lds_l[w * 16 + r];
    }
    float val = o / ll;
    out[(size_t)(i0 + r) * GAT_D + c] = (val > 0.f) ? val : (__expf(val) - 1.f);
  }
}

// ---------------------------------------------------------------------------
extern "C" void kernel_launch(void* const* d_in, const int* in_sizes, int n_in,
                              void* d_out, int out_size, void* d_ws, size_t ws_size,
                              hipStream_t stream) {
  const float* h = (const float*)d_in[0];
  const float* A = (const float*)d_in[1];
  const float* W = (const float*)d_in[2];
  const float* a = (const float*)d_in[3];
  float* out = (float*)d_out;

  // ws layout: [0,1K) bmax | [4K,+32K) s_src | [36864,+32K) s_dst | [69632,+1M) WhT
  const size_t need = 69632 + (size_t)GAT_D * GAT_N * 2;
  if (ws_size < need) return;
  float* bmax = (float*)d_ws;
  float* s_src = (float*)((char*)d_ws + 4096);
  float* s_dst = (float*)((char*)d_ws + 36864);
  short* WhT = (short*)((char*)d_ws + 69632);

  k_prep<<<dim3(256), dim3(256), 0, stream>>>(h, W, a, s_src, s_dst, WhT, bmax);
  k_attn<<<dim3(GAT_N / BM), dim3(512), 0, stream>>>(A, s_src, s_dst, WhT, bmax, out);
}